// Round 5
// baseline (329.965 us; speedup 1.0000x reference)
//
#include <hip/hip_runtime.h>
#include <math.h>

// Spectral_Filter_Transform: per-channel rfft -> keep top-16 |X| bins -> irfft
// (= sum of 16 cosines) -> flip-pad 12 -> 25-tap periodic-Hamming average.
//
// Pipeline:
//   K1 : transpose x (B,T,F) -> ws (B,F,T)
//   K2a: per-channel radix-16^3 register FFT + top-k; writes 16 (f,re,im)
//        tuples into the channel's own (dead) ws region + cos/sin table
//   K2b: per (b, t-tile) block: rebuild xf for 128 channels from tuples
//        (16 interleaved rotation chains), 25-tap conv, write out in
//        (B,T,F) order fully coalesced.  (no output transpose kernel)
// Fallback single-kernel version if ws is too small.

#define NN     4096
#define LOGN   12
#define NT     256
#define EPT    16      // NN / NT
#define KTOP   16
#define WSZ    25
#define HALFW  12
#define FDIM   128
#define BATCH  32
#define TT     64      // K2b t-tile
#define TROWS  (TT + 2 * HALFW)   // 88
#define TWO_PI 6.283185307179586f

// skew: spreads power-of-2 LDS strides across banks; preserves float4 groups.
__device__ __forceinline__ int swz(int a) { return a + (a >> 5); }

#define CMUL(r, i, wr_, wi_) { float _r = (r); (r) = _r * (wr_) - (i) * (wi_); (i) = _r * (wi_) + (i) * (wr_); }
#define MULNI(r, i)          { float _r = (r); (r) = (i); (i) = -_r; }   // *(-i)

// 16-point forward DFT (W16 = e^{-2pi i/16}) fully in registers, natural order.
__device__ __forceinline__ void dft16(float (&zr)[16], float (&zi)[16])
{
    const float C1 = 0.92387953251128674f;
    const float S1 = 0.38268343236508978f;
    const float R2 = 0.70710678118654752f;
    float yr[16], yi[16];
    #pragma unroll
    for (int n2 = 0; n2 < 4; ++n2) {
        float ar = zr[n2],      ai = zi[n2];
        float br = zr[4 + n2],  bi = zi[4 + n2];
        float cr = zr[8 + n2],  ci = zi[8 + n2];
        float dr = zr[12 + n2], di = zi[12 + n2];
        float t0r = ar + cr, t0i = ai + ci;
        float t1r = ar - cr, t1i = ai - ci;
        float t2r = br + dr, t2i = bi + di;
        float t3r = br - dr, t3i = bi - di;
        yr[n2]      = t0r + t2r;  yi[n2]      = t0i + t2i;
        yr[4 + n2]  = t1r + t3i;  yi[4 + n2]  = t1i - t3r;
        yr[8 + n2]  = t0r - t2r;  yi[8 + n2]  = t0i - t2i;
        yr[12 + n2] = t1r - t3i;  yi[12 + n2] = t1i + t3r;
    }
    CMUL(yr[5],  yi[5],  C1, -S1);
    CMUL(yr[6],  yi[6],  R2, -R2);
    CMUL(yr[7],  yi[7],  S1, -C1);
    CMUL(yr[9],  yi[9],  R2, -R2);
    MULNI(yr[10], yi[10]);
    CMUL(yr[11], yi[11], -R2, -R2);
    CMUL(yr[13], yi[13], S1, -C1);
    CMUL(yr[14], yi[14], -R2, -R2);
    CMUL(yr[15], yi[15], -C1, S1);
    #pragma unroll
    for (int k1 = 0; k1 < 4; ++k1) {
        float ar = yr[k1 * 4 + 0], ai = yi[k1 * 4 + 0];
        float br = yr[k1 * 4 + 1], bi = yi[k1 * 4 + 1];
        float cr = yr[k1 * 4 + 2], ci = yi[k1 * 4 + 2];
        float dr = yr[k1 * 4 + 3], di = yi[k1 * 4 + 3];
        float t0r = ar + cr, t0i = ai + ci;
        float t1r = ar - cr, t1i = ai - ci;
        float t2r = br + dr, t2i = bi + di;
        float t3r = br - dr, t3i = bi - di;
        zr[k1]      = t0r + t2r;  zi[k1]      = t0i + t2i;
        zr[4 + k1]  = t1r + t3i;  zi[4 + k1]  = t1i - t3r;
        zr[8 + k1]  = t0r - t2r;  zi[8 + k1]  = t0i - t2i;
        zr[12 + k1] = t1r - t3i;  zi[12 + k1] = t1i + t3r;
    }
}

// ---------------------------------------------------------------- transpose
__global__ __launch_bounds__(256)
void transpose_kernel(const float* __restrict__ in, float* __restrict__ out,
                      int R, int C)
{
    __shared__ float tile[64][65];
    const int b = blockIdx.z;
    const float* pin  = in  + (size_t)b * R * C;
    float*       pout = out + (size_t)b * R * C;
    const int r0 = blockIdx.y * 64, c0 = blockIdx.x * 64;
    const int tc4 = (threadIdx.x & 15) * 4;
    const int tr  = threadIdx.x >> 4;
    #pragma unroll
    for (int i = 0; i < 4; ++i) {
        int r = tr + i * 16;
        float4 v = *(const float4*)&pin[(size_t)(r0 + r) * C + c0 + tc4];
        tile[r][tc4 + 0] = v.x; tile[r][tc4 + 1] = v.y;
        tile[r][tc4 + 2] = v.z; tile[r][tc4 + 3] = v.w;
    }
    __syncthreads();
    #pragma unroll
    for (int i = 0; i < 4; ++i) {
        int r = tr + i * 16;
        float4 v;
        v.x = tile[tc4 + 0][r]; v.y = tile[tc4 + 1][r];
        v.z = tile[tc4 + 2][r]; v.w = tile[tc4 + 3][r];
        *(float4*)&pout[(size_t)(c0 + r) * R + r0 + tc4] = v;
    }
}

// ---------------------------------------------------------------- K2a
// FFT + topk; writes 48-float tuple into own channel region; blocks 0/1 dump
// the cos / -sin halves of the twiddle table to ws[48..2095] / ws[4144..6191].
__global__ __launch_bounds__(NT, 3)
void spectral_fft_topk_kernel(float* __restrict__ ws)
{
    __shared__ float s_re[NN + (NN >> 5)];
    __shared__ float s_im[NN + (NN >> 5)];
    __shared__ float s_tw[NN + (NN >> 5)];   // cos(2πq/N) @swz(q), -sin @swz(q+2048)
    __shared__ float s_rv[8];
    __shared__ int   s_rk[8];
    __shared__ int   s_kf[KTOP];
    __shared__ float s_kr[KTOP];
    __shared__ float s_ki[KTOP];

    const int tid = threadIdx.x;
    float* chan = ws + (size_t)blockIdx.x * NN;

    // global load first: stride-256 ownership, wave-level fully coalesced
    float zr[16], zi[16];
    #pragma unroll
    for (int r = 0; r < 16; ++r) { zr[r] = chan[tid + (r << 8)]; zi[r] = 0.0f; }

    for (int i = tid; i < NN / 2; i += NT) {
        float sn, cs;
        sincosf(-TWO_PI * (float)i / (float)NN, &sn, &cs);
        s_tw[swz(i)]          = cs;
        s_tw[swz(i + NN / 2)] = sn;
    }

    // ---- stage 0 (L=4096)
    dft16(zr, zi);
    __syncthreads();

    {   // twiddle W_4096^{tid*u}; scatter to LDS at tid+256u
        float dr = s_tw[swz(tid)], di = s_tw[swz(tid + 2048)];
        float wr = dr, wi = di;
        #pragma unroll
        for (int u = 1; u < 16; ++u) {
            CMUL(zr[u], zi[u], wr, wi);
            float nr = wr * dr - wi * di; wi = wr * di + wi * dr; wr = nr;
        }
        #pragma unroll
        for (int u = 0; u < 16; ++u) {
            int a = swz(tid + (u << 8));
            s_re[a] = zr[u]; s_im[a] = zi[u];
        }
    }
    __syncthreads();

    {   // ---- stage 1 (L=256)
        const int p = tid & 15;
        const int b0 = ((tid >> 4) << 8) + p;
        #pragma unroll
        for (int r = 0; r < 16; ++r) {
            int a = swz(b0 + (r << 4));
            zr[r] = s_re[a]; zi[r] = s_im[a];
        }
        dft16(zr, zi);
        float dr = s_tw[swz(p << 4)], di = s_tw[swz((p << 4) + 2048)];
        float wr = dr, wi = di;
        #pragma unroll
        for (int u = 1; u < 16; ++u) {
            CMUL(zr[u], zi[u], wr, wi);
            float nr = wr * dr - wi * di; wi = wr * di + wi * dr; wr = nr;
        }
        #pragma unroll
        for (int u = 0; u < 16; ++u) {
            int a = swz(b0 + (u << 4));
            s_re[a] = zr[u]; s_im[a] = zi[u];
        }
    }
    __syncthreads();

    {   // ---- stage 2 (L=16): results stay in registers
        #pragma unroll
        for (int r = 0; r < 16; ++r) {
            int a = swz((tid << 4) + r);
            zr[r] = s_re[a]; zi[r] = s_im[a];
        }
        dft16(zr, zi);
    }

    // bin f = 256*u + fbase, fbase = nibbleswap(tid); valid: u<8, or u==8 & tid==0
    const int fbase = ((tid & 15) << 4) | (tid >> 4);
    float mg[9];
    float lmax = -1.0f; int lk = 0x7fffffff;
    #pragma unroll
    for (int u = 0; u < 9; ++u) {
        float v = zr[u] * zr[u] + zi[u] * zi[u];
        if (u == 8 && fbase != 0) v = -1.0f;
        mg[u] = v;
        if (v > lmax) { lmax = v; lk = (u << 8) + fbase; }
    }

    for (int r = 0; r < KTOP; ++r) {
        float bv = lmax; int bk = lk;
        #pragma unroll
        for (int off = 32; off > 0; off >>= 1) {
            float ov = __shfl_down(bv, off);
            int   ok = __shfl_down(bk, off);
            if (ov > bv || (ov == bv && ok < bk)) { bv = ov; bk = ok; }
        }
        const int buf = (r & 1) << 2;
        if ((tid & 63) == 0) { s_rv[buf + (tid >> 6)] = bv; s_rk[buf + (tid >> 6)] = bk; }
        __syncthreads();
        bv = s_rv[buf]; bk = s_rk[buf];
        #pragma unroll
        for (int w2 = 1; w2 < 4; ++w2) {
            float ov = s_rv[buf + w2]; int ok = s_rk[buf + w2];
            if (ov > bv || (ov == bv && ok < bk)) { bv = ov; bk = ok; }
        }
        if (lmax == bv && lk == bk) {
            const int uw = bk >> 8;
            s_kf[r] = bk;
            #pragma unroll
            for (int u2 = 0; u2 < 9; ++u2) {
                if (u2 == uw) { s_kr[r] = zr[u2]; s_ki[r] = zi[u2]; mg[u2] = -1.0f; }
            }
            lmax = -1.0f; lk = 0x7fffffff;
            #pragma unroll
            for (int u2 = 0; u2 < 9; ++u2) {
                float v = mg[u2];
                if (v > lmax) { lmax = v; lk = (u2 << 8) + fbase; }
            }
        }
    }
    __syncthreads();

    // tuple write: [0..15] freq (int bits), [16..31] re, [32..47] im
    if (tid < KTOP) {
        chan[tid]          = __int_as_float(s_kf[tid]);
        chan[KTOP + tid]   = s_kr[tid];
        chan[2 * KTOP + tid] = s_ki[tid];
    }
    // table dump (channels 0/1 own regions are dead): cos half / -sin half
    if (blockIdx.x < 2) {
        const int off = blockIdx.x ? 2048 : 0;
        for (int i = tid; i < 2048; i += NT)
            chan[48 + i] = s_tw[swz(i + off)];
    }
}

// ---------------------------------------------------------------- K2b
// grid: (BATCH * NN/TT). Block = (batch b, t-tile). 128 channels per block.
__global__ __launch_bounds__(NT, 2)
void recon_conv_kernel(const float* __restrict__ ws, float* __restrict__ out)
{
    __shared__ float s_xf[TROWS][FDIM];    // 88 x 128
    __shared__ float s_fj[KTOP][FDIM];     // freq as int bits
    __shared__ float s_vr[KTOP][FDIM];
    __shared__ float s_vi[KTOP][FDIM];
    __shared__ float s_w[WSZ];
    __shared__ float s_wsum;

    const int tid = threadIdx.x;
    const int b   = blockIdx.x >> 6;       // 64 t-tiles per batch
    const int t0  = (blockIdx.x & 63) * TT;

    if (tid < WSZ)
        s_w[tid] = 0.54f - 0.46f * cosf(TWO_PI * (float)tid / (float)WSZ);

    // tuple load: 2 threads per channel, 24 consecutive floats each
    {
        const float* tup = ws + (size_t)b * FDIM * NN;
        const int ch = tid >> 1, half = tid & 1;
        const float* src = tup + (size_t)ch * NN + half * 24;
        #pragma unroll
        for (int k = 0; k < 24; ++k) {
            float v = src[k];
            int p = half * 24 + k;
            int j = p & 15, kind = p >> 4;
            if (kind == 0)      s_fj[j][ch] = v;
            else if (kind == 1) s_vr[j][ch] = v;
            else                s_vi[j][ch] = v;
        }
    }
    __syncthreads();

    if (tid == 0) {     // sequential fp32 sum, matching jnp.sum(w)
        float a = 0.0f;
        for (int i = 0; i < WSZ; ++i) a += s_w[i];
        s_wsum = a;
    }

    const float* cosT  = ws + 48;          // cos(2πq/N),  q<2048
    const float* nsinT = ws + NN + 48;     // -sin(2πq/N), q<2048

    // ---- phase A: xf rows [0,88) -> t = t0-12+row (wrapped mod N; wrapped
    // rows are only read via mirroring, which lands on valid rows).
    {
        const int f  = tid & 127;
        const int st = tid >> 7;           // strip 0: rows 0..43, strip 1: 44..87
        const int r0 = st * 44;
        const int ts = (t0 - HALFW + r0) & (NN - 1);

        float cr[16], ci[16], dc[16], ds[16], vr[16], vi[16];
        #pragma unroll
        for (int j = 0; j < 16; ++j) {
            int   fj = __float_as_int(s_fj[j][f]);
            float ar = s_vr[j][f], ai = s_vi[j][f];
            bool  dcny = (fj == 0) | (fj == NN / 2);
            float sc = dcny ? (1.0f / (float)NN) : (2.0f / (float)NN);
            vr[j] = ar * sc;
            vi[j] = dcny ? 0.0f : ai * sc;
            int q0 = (fj * ts) & (NN - 1);
            int q1 = q0 & 2047;
            float c  = cosT[q1], ns = nsinT[q1];
            if (q0 & 2048) { cr[j] = -c; ci[j] =  ns; }
            else           { cr[j] =  c; ci[j] = -ns; }
            int qd = fj & 2047;
            float cd = cosT[qd], nsd = nsinT[qd];
            if (fj & 2048) { dc[j] = -cd; ds[j] =  nsd; }
            else           { dc[j] =  cd; ds[j] = -nsd; }
        }
        for (int rr = 0; rr < 44; ++rr) {
            float a0 = 0.0f, a1 = 0.0f, a2 = 0.0f, a3 = 0.0f;
            #pragma unroll
            for (int j = 0; j < 16; j += 4) {
                a0 += vr[j]     * cr[j]     - vi[j]     * ci[j];
                a1 += vr[j + 1] * cr[j + 1] - vi[j + 1] * ci[j + 1];
                a2 += vr[j + 2] * cr[j + 2] - vi[j + 2] * ci[j + 2];
                a3 += vr[j + 3] * cr[j + 3] - vi[j + 3] * ci[j + 3];
            }
            s_xf[r0 + rr][f] = (a0 + a1) + (a2 + a3);
            #pragma unroll
            for (int j = 0; j < 16; ++j) {
                float nc = cr[j] * dc[j] - ci[j] * ds[j];
                ci[j] = ci[j] * dc[j] + cr[j] * ds[j];
                cr[j] = nc;
            }
        }
    }
    __syncthreads();

    // ---- phase B: sliding 25-tap conv, direct coalesced (B,T,F) store
    {
        const int f  = tid & 127;
        const int hb = tid >> 7;           // 2 halves of 32 t each
        const float rinv = 1.0f / s_wsum;
        const int tb = t0 + hb * 32;
        const int abase = tb - HALFW;
        float* outp = out + ((size_t)b * NN) * FDIM + f;

        float win[WSZ];
        #pragma unroll
        for (int i = 0; i < WSZ; ++i) {
            int a  = abase + i;
            int ap = a < 0 ? -1 - a : (a >= NN ? 2 * NN - 1 - a : a);
            win[i] = s_xf[ap - t0 + HALFW][f];
        }
        #pragma unroll
        for (int k = 0; k < 32; ++k) {
            float acc = 0.0f;
            #pragma unroll
            for (int i = 0; i < WSZ; ++i) acc += win[i] * s_w[i];
            outp[(size_t)(tb + k) * FDIM] = acc * rinv;
            if (k < 31) {
                #pragma unroll
                for (int i = 0; i < WSZ - 1; ++i) win[i] = win[i + 1];
                int a  = abase + k + WSZ;
                int ap = a < 0 ? -1 - a : (a >= NN ? 2 * NN - 1 - a : a);
                win[WSZ - 1] = s_xf[ap - t0 + HALFW][f];
            }
        }
    }
}

// ---------------------------------------------------------------- fallback
__global__ __launch_bounds__(NT, 3)
void spectral_filter_fallback(const float* __restrict__ x, float* __restrict__ out)
{
    __shared__ float s_re[NN + (NN >> 5)];
    __shared__ float s_im[NN];
    __shared__ float s_tw[NN];
    __shared__ float s_w[WSZ];
    __shared__ float s_wsum;
    __shared__ float s_rv[NT / 64];
    __shared__ int   s_ri[NT / 64];
    __shared__ int   s_kf[KTOP];
    __shared__ float s_kr[KTOP];
    __shared__ float s_ki[KTOP];

    const int tid = threadIdx.x;
    const int c   = blockIdx.x;
    const int b   = c >> 7;
    const int f   = c & (FDIM - 1);
    const size_t base = (size_t)b * NN * FDIM + f;

    if (tid < WSZ)
        s_w[tid] = 0.54f - 0.46f * cosf(TWO_PI * (float)tid / (float)WSZ);

    for (int i = tid; i < NN / 2; i += NT) {
        float sn, cs;
        sincosf(-TWO_PI * (float)i / (float)NN, &sn, &cs);
        s_tw[i]          = cs;
        s_tw[i + NN / 2] = sn;
    }

    #pragma unroll
    for (int i = 0; i < EPT; ++i) {
        int j = tid + i * NT;
        int t = (int)(__brev((unsigned)j) >> (32 - LOGN));
        s_re[j] = x[base + (size_t)t * FDIM];
        s_im[j] = 0.0f;
    }
    __syncthreads();

    if (tid == 0) {
        float a = 0.0f;
        for (int i = 0; i < WSZ; ++i) a += s_w[i];
        s_wsum = a;
    }

    for (int s = 1; s <= LOGN; ++s) {
        const int half = 1 << (s - 1);
        const int tsh  = LOGN - s;
        #pragma unroll
        for (int i = 0; i < EPT / 2; ++i) {
            int j  = tid + i * NT;
            int p  = j & (half - 1);
            int i0 = ((j >> (s - 1)) << s) + p;
            int i1 = i0 + half;
            int q  = p << tsh;
            float wr = s_tw[q], wi = s_tw[q + NN / 2];
            float ar = s_re[i0], ai = s_im[i0];
            float br = s_re[i1], bi = s_im[i1];
            float tr = br * wr - bi * wi;
            float ti = br * wi + bi * wr;
            s_re[i0] = ar + tr;  s_im[i0] = ai + ti;
            s_re[i1] = ar - tr;  s_im[i1] = ai - ti;
        }
        __syncthreads();
    }

    for (int i = tid; i < NN / 2 + 1; i += NT) {
        float rr = s_re[i], ii = s_im[i];
        s_tw[i] = rr * rr + ii * ii;
    }
    __syncthreads();

    for (int r = 0; r < KTOP; ++r) {
        float best = -1.0f; int bidx = 0x7fffffff;
        for (int i = tid; i < NN / 2 + 1; i += NT) {
            float v = s_tw[i];
            if (v > best) { best = v; bidx = i; }
        }
        #pragma unroll
        for (int off = 32; off > 0; off >>= 1) {
            float ov = __shfl_down(best, off);
            int   oi = __shfl_down(bidx, off);
            if (ov > best || (ov == best && oi < bidx)) { best = ov; bidx = oi; }
        }
        const int wid = tid >> 6;
        if ((tid & 63) == 0) { s_rv[wid] = best; s_ri[wid] = bidx; }
        __syncthreads();
        if (tid == 0) {
            float bv = s_rv[0]; int bx = s_ri[0];
            #pragma unroll
            for (int w2 = 1; w2 < NT / 64; ++w2) {
                float ov = s_rv[w2]; int oi = s_ri[w2];
                if (ov > bv || (ov == bv && oi < bx)) { bv = ov; bx = oi; }
            }
            s_kf[r] = bx;
            s_kr[r] = s_re[bx];
            s_ki[r] = s_im[bx];
            s_tw[bx] = -1.0f;
        }
        __syncthreads();
    }

    const int t0 = tid * EPT;
    float xf[EPT];
    #pragma unroll
    for (int i = 0; i < EPT; ++i) xf[i] = 0.0f;

    for (int r = 0; r < KTOP; ++r) {
        const int fj = s_kf[r];
        float vr = s_kr[r], vi = s_ki[r];
        float sc = 2.0f;
        if (fj == 0 || fj == NN / 2) { sc = 1.0f; vi = 0.0f; }
        vr *= sc; vi *= sc;
        const int ph0 = (fj * t0) & (NN - 1);
        float c0, s0, dc, ds;
        sincosf((float)ph0 * (TWO_PI / (float)NN), &s0, &c0);
        sincosf((float)fj  * (TWO_PI / (float)NN), &ds, &dc);
        float cr = c0, ci = s0;
        #pragma unroll
        for (int i = 0; i < EPT; ++i) {
            xf[i] += vr * cr - vi * ci;
            float nc = cr * dc - ci * ds;
            ci = ci * dc + cr * ds;
            cr = nc;
        }
    }
    __syncthreads();

    #pragma unroll
    for (int i = 0; i < EPT; ++i)
        s_re[swz(t0 + i)] = xf[i] * (1.0f / (float)NN);
    __syncthreads();

    float win[EPT + WSZ - 1];
    #pragma unroll
    for (int i = 0; i < EPT + WSZ - 1; ++i) {
        int a = t0 + i - HALFW;
        if (a < 0)        a = -1 - a;
        else if (a >= NN) a = 2 * NN - 1 - a;
        win[i] = s_re[swz(a)];
    }

    const float rinv = 1.0f / s_wsum;
    float acc[EPT];
    #pragma unroll
    for (int t = 0; t < EPT; ++t) acc[t] = 0.0f;
    #pragma unroll
    for (int i = 0; i < WSZ; ++i) {
        const float wv = s_w[i];
        #pragma unroll
        for (int t = 0; t < EPT; ++t) acc[t] += win[t + i] * wv;
    }
    #pragma unroll
    for (int t = 0; t < EPT; ++t)
        out[base + (size_t)(t0 + t) * FDIM] = acc[t] * rinv;
}

extern "C" void kernel_launch(void* const* d_in, const int* in_sizes, int n_in,
                              void* d_out, int out_size, void* d_ws, size_t ws_size,
                              hipStream_t stream)
{
    const float* x = (const float*)d_in[0];
    float* out = (float*)d_out;
    const size_t need = (size_t)BATCH * FDIM * NN * sizeof(float);
    if (ws_size >= need) {
        float* ws = (float*)d_ws;
        transpose_kernel<<<dim3(FDIM / 64, NN / 64, BATCH), 256, 0, stream>>>(x, ws, NN, FDIM);
        spectral_fft_topk_kernel<<<dim3(BATCH * FDIM), NT, 0, stream>>>(ws);
        recon_conv_kernel<<<dim3(BATCH * (NN / TT)), NT, 0, stream>>>(ws, out);
    } else {
        spectral_filter_fallback<<<dim3(BATCH * FDIM), NT, 0, stream>>>(x, out);
    }
}